// Round 1
// baseline (519.030 us; speedup 1.0000x reference)
//
#include <hip/hip_runtime.h>
#include <stdint.h>

// EdgeConv: B=256, N=128, C=64, K=16
// Kernel 1: exact-fp32 KNN (replicates jax d = r - 2*p.p' + r' with no FMA
//           contraction; top-(K+1) with (dist,idx) lexicographic keys = jax
//           top_k stable tie-break; drop rank 0).
// Kernel 2: fused MLP. Weights staged in LDS once/block (80KB). BN folded to
//           per-channel affine. Layer-0 center half computed once per row.
//           4 waves/block, 1 row per wave, 4k x 4c register tiles, transposed
//           activation buffers (row stride 20 floats keeps b128 alignment and
//           breaks the 64-float power-of-2 stride).

#define NB 256
#define NP 128
#define KK 16
#define CD 64
#define EPSV 1e-3f
#define AST 20  // activation row stride (floats); 80B = 16B-aligned, non-pow2

__device__ __forceinline__ unsigned int f2ord(float f) {
  unsigned int u = __float_as_uint(f);
  return (u & 0x80000000u) ? ~u : (u | 0x80000000u);
}

__global__ __launch_bounds__(256) void knn_kernel(const float* __restrict__ pts,
                                                  int* __restrict__ knn) {
  const int wv = threadIdx.x >> 6;
  const int lane = threadIdx.x & 63;
  const int row = blockIdx.x * 4 + wv;   // row = b*128 + n
  const int b = row >> 7;
  const int n = row & (NP - 1);
  const float* pb = pts + b * NP * 2;
  const float xn = pb[2 * n];
  const float yn = pb[2 * n + 1];
  // r_n = x*x + y*y exactly as numpy (mul, mul, add; no fma)
  const float rn = __fadd_rn(__fmul_rn(xn, xn), __fmul_rn(yn, yn));

  unsigned long long key[2];
#pragma unroll
  for (int h = 0; h < 2; ++h) {
    const int j = lane + h * 64;
    const float xj = pb[2 * j];
    const float yj = pb[2 * j + 1];
    const float rj = __fadd_rn(__fmul_rn(xj, xj), __fmul_rn(yj, yj));
    const float dot = __fadd_rn(__fmul_rn(xn, xj), __fmul_rn(yn, yj));
    // d = (r_n - 2*dot) + r_j  -- matches (r - 2*einsum) + r^T left-assoc
    const float d = __fadd_rn(__fsub_rn(rn, __fmul_rn(2.0f, dot)), rj);
    key[h] = ((unsigned long long)f2ord(d) << 32) | (unsigned int)j;
  }

  // iterative selection of the 17 smallest keys; drop the first (self)
  for (int it = 0; it < KK + 1; ++it) {
    unsigned long long m = key[0] < key[1] ? key[0] : key[1];
#pragma unroll
    for (int off = 32; off > 0; off >>= 1) {
      unsigned long long o = __shfl_xor(m, off);
      if (o < m) m = o;
    }
    if (it > 0 && lane == 0) knn[row * KK + (it - 1)] = (int)(m & 0xFFFFFFFFULL);
    if (key[0] == m) key[0] = ~0ULL;
    if (key[1] == m) key[1] = ~0ULL;
  }
}

__global__ __launch_bounds__(256) void mlp_kernel(
    const float* __restrict__ feat, const int* __restrict__ knn,
    const float* __restrict__ w0, const float* __restrict__ g0,
    const float* __restrict__ b0, const float* __restrict__ m0,
    const float* __restrict__ v0, const float* __restrict__ w1,
    const float* __restrict__ g1, const float* __restrict__ b1,
    const float* __restrict__ m1, const float* __restrict__ v1,
    const float* __restrict__ w2, const float* __restrict__ g2,
    const float* __restrict__ b2, const float* __restrict__ m2,
    const float* __restrict__ v2, const float* __restrict__ wsc,
    const float* __restrict__ gsc, const float* __restrict__ bsc,
    const float* __restrict__ msc, const float* __restrict__ vsc,
    float* __restrict__ out) {
  __shared__ float w0s[128 * 64];   // 32 KB  [i][c]
  __shared__ float w1s[64 * 64];    // 16 KB
  __shared__ float w2s[64 * 64];    // 16 KB
  __shared__ float wscs[64 * 64];   // 16 KB
  __shared__ float actA[4][64 * AST];  // per-wave transposed acts (ping)
  __shared__ float actB[4][64 * AST];  // (pong)
  __shared__ float cfw[4][64];         // per-wave center features

  const int tid = threadIdx.x;
  const int wv = tid >> 6;
  const int lane = tid & 63;
  const int kq = lane >> 4;   // 0..3 -> k-tile
  const int cg = lane & 15;   // 0..15 -> c-tile
  const int c0 = cg * 4;
  const int kq4 = kq * 4;

  // ---- stage weights (coalesced float4) ----
  for (int i = tid * 4; i < 128 * 64; i += 1024)
    *(float4*)&w0s[i] = *(const float4*)&w0[i];
  for (int i = tid * 4; i < 64 * 64; i += 1024) {
    *(float4*)&w1s[i] = *(const float4*)&w1[i];
    *(float4*)&w2s[i] = *(const float4*)&w2[i];
    *(float4*)&wscs[i] = *(const float4*)&wsc[i];
  }

  // ---- folded BN params for this lane's 4 channels ----
  float s0v[4], bb0[4], s1v[4], bb1[4], s2v[4], bb2[4], sscv[4], bbsc[4];
#pragma unroll
  for (int cc = 0; cc < 4; ++cc) {
    const int c = c0 + cc;
    float s;
    s = g0[c] / sqrtf(v0[c] + EPSV); s0v[cc] = s; bb0[cc] = b0[c] - m0[c] * s;
    s = g1[c] / sqrtf(v1[c] + EPSV); s1v[cc] = s; bb1[cc] = b1[c] - m1[c] * s;
    s = g2[c] / sqrtf(v2[c] + EPSV); s2v[cc] = s; bb2[cc] = b2[c] - m2[c] * s;
    s = gsc[c] / sqrtf(vsc[c] + EPSV); sscv[cc] = s; bbsc[cc] = bsc[c] - msc[c] * s;
  }
  __syncthreads();

  for (int rg = 0; rg < 4; ++rg) {
    const int row = blockIdx.x * 16 + rg * 4 + wv;  // row = b*128 + n
    const int b = row >> 7;
    __syncthreads();  // protect cfw/act reuse across rg iterations

    // ---- stage center features ----
    if (lane < 16)
      *(float4*)&cfw[wv][lane * 4] = *(const float4*)&feat[row * 64 + lane * 4];
    __syncthreads();

    // ---- stage diffs, transposed: actA[i][k] = f[nbr][i] - cf[i] ----
    {
      const int k = lane >> 2;
      const int part = lane & 3;
      const int j = knn[row * KK + k];
      const float* fr = feat + (b * NP + j) * 64;
#pragma unroll
      for (int q = 0; q < 4; ++q) {
        const int i0 = part * 16 + q * 4;
        const float4 vn = *(const float4*)&fr[i0];
        const float4 cf = *(const float4*)&cfw[wv][i0];
        actA[wv][(i0 + 0) * AST + k] = vn.x - cf.x;
        actA[wv][(i0 + 1) * AST + k] = vn.y - cf.y;
        actA[wv][(i0 + 2) * AST + k] = vn.z - cf.z;
        actA[wv][(i0 + 3) * AST + k] = vn.w - cf.w;
      }
    }
    __syncthreads();

    // ---- layer 0 center half: cp[c] = sum_i cf[i]*w0[i][c] ----
    float cp[4] = {0.f, 0.f, 0.f, 0.f};
#pragma unroll 8
    for (int i = 0; i < 64; ++i) {
      const float a = cfw[wv][i];
      const float4 w = *(float4*)&w0s[i * 64 + c0];
      cp[0] = fmaf(a, w.x, cp[0]); cp[1] = fmaf(a, w.y, cp[1]);
      cp[2] = fmaf(a, w.z, cp[2]); cp[3] = fmaf(a, w.w, cp[3]);
    }

    // ---- layer 0 diff half + BN + ReLU ----
    float acc[4][4];
#pragma unroll
    for (int kk = 0; kk < 4; ++kk)
#pragma unroll
      for (int cc = 0; cc < 4; ++cc) acc[kk][cc] = cp[cc];
#pragma unroll 4
    for (int i = 0; i < 64; ++i) {
      const float4 a4 = *(float4*)&actA[wv][i * AST + kq4];
      const float4 w4 = *(float4*)&w0s[(64 + i) * 64 + c0];
      const float aa[4] = {a4.x, a4.y, a4.z, a4.w};
      const float ww[4] = {w4.x, w4.y, w4.z, w4.w};
#pragma unroll
      for (int kk = 0; kk < 4; ++kk)
#pragma unroll
        for (int cc = 0; cc < 4; ++cc)
          acc[kk][cc] = fmaf(aa[kk], ww[cc], acc[kk][cc]);
    }
#pragma unroll
    for (int cc = 0; cc < 4; ++cc) {
      float4 st;
      st.x = fmaxf(fmaf(acc[0][cc], s0v[cc], bb0[cc]), 0.f);
      st.y = fmaxf(fmaf(acc[1][cc], s0v[cc], bb0[cc]), 0.f);
      st.z = fmaxf(fmaf(acc[2][cc], s0v[cc], bb0[cc]), 0.f);
      st.w = fmaxf(fmaf(acc[3][cc], s0v[cc], bb0[cc]), 0.f);
      *(float4*)&actB[wv][(c0 + cc) * AST + kq4] = st;  // transposed for L1
    }
    __syncthreads();

    // ---- layer 1 + BN + ReLU ----
#pragma unroll
    for (int kk = 0; kk < 4; ++kk)
#pragma unroll
      for (int cc = 0; cc < 4; ++cc) acc[kk][cc] = 0.f;
#pragma unroll 4
    for (int i = 0; i < 64; ++i) {
      const float4 a4 = *(float4*)&actB[wv][i * AST + kq4];
      const float4 w4 = *(float4*)&w1s[i * 64 + c0];
      const float aa[4] = {a4.x, a4.y, a4.z, a4.w};
      const float ww[4] = {w4.x, w4.y, w4.z, w4.w};
#pragma unroll
      for (int kk = 0; kk < 4; ++kk)
#pragma unroll
        for (int cc = 0; cc < 4; ++cc)
          acc[kk][cc] = fmaf(aa[kk], ww[cc], acc[kk][cc]);
    }
#pragma unroll
    for (int cc = 0; cc < 4; ++cc) {
      float4 st;
      st.x = fmaxf(fmaf(acc[0][cc], s1v[cc], bb1[cc]), 0.f);
      st.y = fmaxf(fmaf(acc[1][cc], s1v[cc], bb1[cc]), 0.f);
      st.z = fmaxf(fmaf(acc[2][cc], s1v[cc], bb1[cc]), 0.f);
      st.w = fmaxf(fmaf(acc[3][cc], s1v[cc], bb1[cc]), 0.f);
      *(float4*)&actA[wv][(c0 + cc) * AST + kq4] = st;
    }
    __syncthreads();

    // ---- layer 2 + BN + ReLU (kept in regs) ----
#pragma unroll
    for (int kk = 0; kk < 4; ++kk)
#pragma unroll
      for (int cc = 0; cc < 4; ++cc) acc[kk][cc] = 0.f;
#pragma unroll 4
    for (int i = 0; i < 64; ++i) {
      const float4 a4 = *(float4*)&actA[wv][i * AST + kq4];
      const float4 w4 = *(float4*)&w2s[i * 64 + c0];
      const float aa[4] = {a4.x, a4.y, a4.z, a4.w};
      const float ww[4] = {w4.x, w4.y, w4.z, w4.w};
#pragma unroll
      for (int kk = 0; kk < 4; ++kk)
#pragma unroll
        for (int cc = 0; cc < 4; ++cc)
          acc[kk][cc] = fmaf(aa[kk], ww[cc], acc[kk][cc]);
    }
    // mean over k: sum this lane's 4 k, then reduce across the 4 kq groups
    float pool[4];
#pragma unroll
    for (int cc = 0; cc < 4; ++cc) {
      float p = fmaxf(fmaf(acc[0][cc], s2v[cc], bb2[cc]), 0.f) +
                fmaxf(fmaf(acc[1][cc], s2v[cc], bb2[cc]), 0.f) +
                fmaxf(fmaf(acc[2][cc], s2v[cc], bb2[cc]), 0.f) +
                fmaxf(fmaf(acc[3][cc], s2v[cc], bb2[cc]), 0.f);
      p += __shfl_xor(p, 16);
      p += __shfl_xor(p, 32);
      pool[cc] = p * (1.0f / 16.0f);
    }

    // ---- shortcut GEMV + BN, add, ReLU, store ----
    float sc[4] = {0.f, 0.f, 0.f, 0.f};
#pragma unroll 8
    for (int i = 0; i < 64; ++i) {
      const float a = cfw[wv][i];
      const float4 w = *(float4*)&wscs[i * 64 + c0];
      sc[0] = fmaf(a, w.x, sc[0]); sc[1] = fmaf(a, w.y, sc[1]);
      sc[2] = fmaf(a, w.z, sc[2]); sc[3] = fmaf(a, w.w, sc[3]);
    }
    if (kq == 0) {
      float4 o;
      o.x = fmaxf(fmaf(sc[0], sscv[0], bbsc[0]) + pool[0], 0.f);
      o.y = fmaxf(fmaf(sc[1], sscv[1], bbsc[1]) + pool[1], 0.f);
      o.z = fmaxf(fmaf(sc[2], sscv[2], bbsc[2]) + pool[2], 0.f);
      o.w = fmaxf(fmaf(sc[3], sscv[3], bbsc[3]) + pool[3], 0.f);
      *(float4*)&out[row * 64 + c0] = o;
    }
  }
}

extern "C" void kernel_launch(void* const* d_in, const int* in_sizes, int n_in,
                              void* d_out, int out_size, void* d_ws, size_t ws_size,
                              hipStream_t stream) {
  const float* pts = (const float*)d_in[0];
  const float* feat = (const float*)d_in[1];
  const float* w0 = (const float*)d_in[2];
  const float* g0 = (const float*)d_in[3];
  const float* b0 = (const float*)d_in[4];
  const float* m0 = (const float*)d_in[5];
  const float* v0 = (const float*)d_in[6];
  const float* w1 = (const float*)d_in[7];
  const float* g1 = (const float*)d_in[8];
  const float* b1 = (const float*)d_in[9];
  const float* m1 = (const float*)d_in[10];
  const float* v1 = (const float*)d_in[11];
  const float* w2 = (const float*)d_in[12];
  const float* g2 = (const float*)d_in[13];
  const float* b2 = (const float*)d_in[14];
  const float* m2 = (const float*)d_in[15];
  const float* v2 = (const float*)d_in[16];
  const float* wsc = (const float*)d_in[17];
  const float* gsc = (const float*)d_in[18];
  const float* bsc = (const float*)d_in[19];
  const float* msc = (const float*)d_in[20];
  const float* vsc = (const float*)d_in[21];
  float* out = (float*)d_out;

  int* knn = (int*)d_ws;  // 256*128*16 ints = 2 MB

  knn_kernel<<<dim3(NB * NP / 4), dim3(256), 0, stream>>>(pts, knn);
  mlp_kernel<<<dim3(NB * NP / 16), dim3(256), 0, stream>>>(
      feat, knn, w0, g0, b0, m0, v0, w1, g1, b1, m1, v1, w2, g2, b2, m2, v2,
      wsc, gsc, bsc, msc, vsc, out);
}

// Round 2
// 178.105 us; speedup vs baseline: 2.9142x; 2.9142x over previous
//
#include <hip/hip_runtime.h>
#include <stdint.h>

// EdgeConv B=256,N=128,C=64,K=16 — round 2: MFMA MLP + rank-count KNN.
// knn_kernel: exact-tie u64 keys (validated in round 1), rank = count of
//             smaller keys (order-invariant under mean pooling).
// mlp_kernel: bf16 16x16x32 MFMA. Per wave: 16 rows; per row a 16(k)x128
//             activation tile; weights transposed in LDS (B^T, k-contiguous
//             16B frags). Inter-layer transform via in-place LDS round-trip
//             (in-wave DS ordering => no barriers in row loop). Shortcut =
//             one M=16 MFMA GEMM per wave; its C-layout (row=quad*4+reg)
//             matches the per-row store phase. LDS 70KB -> 2 blocks/CU.

#define KK 16
#define EPSV 1e-3f
#define SW0 136  // w0T / X0 row stride (bf16 elems): 128+8, 16B-multiple
#define SW 72    // 64+8 stride

typedef __bf16 bf16x8 __attribute__((ext_vector_type(8)));
typedef float f32x4 __attribute__((ext_vector_type(4)));
union B8 { uint4 u; bf16x8 v; };

__device__ __forceinline__ unsigned int f2ord(float f) {
  unsigned int u = __float_as_uint(f);
  return (u & 0x80000000u) ? ~u : (u | 0x80000000u);
}
__device__ __forceinline__ unsigned int f2b(float f) {  // fp32->bf16 RNE bits
  unsigned int u = __float_as_uint(f);
  return (u + 0x7FFFu + ((u >> 16) & 1u)) >> 16;
}
__device__ __forceinline__ unsigned int pk(float lo, float hi) {
  return f2b(lo) | (f2b(hi) << 16);
}

__global__ __launch_bounds__(256) void knn_kernel(const float* __restrict__ pts,
                                                  int* __restrict__ knn) {
  __shared__ __align__(16) unsigned long long keys[4][128];
  const int wv = threadIdx.x >> 6;
  const int lane = threadIdx.x & 63;
  const int row = blockIdx.x * 4 + wv;
  const int b = row >> 7;
  const int n = row & 127;
  const float* pb = pts + b * 128 * 2;
  const float xn = pb[2 * n], yn = pb[2 * n + 1];
  const float rn = __fadd_rn(__fmul_rn(xn, xn), __fmul_rn(yn, yn));

  unsigned long long key0, key1;
#pragma unroll
  for (int h = 0; h < 2; ++h) {
    const int j = lane + h * 64;
    const float xj = pb[2 * j], yj = pb[2 * j + 1];
    const float rj = __fadd_rn(__fmul_rn(xj, xj), __fmul_rn(yj, yj));
    const float dot = __fadd_rn(__fmul_rn(xn, xj), __fmul_rn(yn, yj));
    const float d = __fadd_rn(__fsub_rn(rn, __fmul_rn(2.0f, dot)), rj);
    unsigned long long k = ((unsigned long long)f2ord(d) << 32) | (unsigned int)j;
    if (h == 0) key0 = k; else key1 = k;
  }
  keys[wv][lane] = key0;
  keys[wv][lane + 64] = key1;
  // in-wave DS ordering: writes above complete before reads below (same wave)
  int c0 = 0, c1 = 0;
#pragma unroll 8
  for (int j = 0; j < 128; j += 2) {
    const ulonglong2 kp = *(const ulonglong2*)&keys[wv][j];
    c0 += (kp.x < key0); c0 += (kp.y < key0);
    c1 += (kp.x < key1); c1 += (kp.y < key1);
  }
  // ranks unique (idx in low bits); rank 0 = top-1 (dropped), ranks 1..16 kept
  if (c0 >= 1 && c0 <= 16) knn[row * KK + c0 - 1] = lane;
  if (c1 >= 1 && c1 <= 16) knn[row * KK + c1 - 1] = lane + 64;
}

__global__ __launch_bounds__(256, 2) void mlp_kernel(
    const float* __restrict__ feat, const int* __restrict__ knnIdx,
    const float* __restrict__ w0, const float* __restrict__ g0,
    const float* __restrict__ b0, const float* __restrict__ m0,
    const float* __restrict__ v0, const float* __restrict__ w1,
    const float* __restrict__ g1, const float* __restrict__ b1,
    const float* __restrict__ m1, const float* __restrict__ v1,
    const float* __restrict__ w2, const float* __restrict__ g2,
    const float* __restrict__ b2, const float* __restrict__ m2,
    const float* __restrict__ v2, const float* __restrict__ wsc,
    const float* __restrict__ gsc, const float* __restrict__ bsc,
    const float* __restrict__ msc, const float* __restrict__ vsc,
    float* __restrict__ out) {
  __shared__ __align__(16) unsigned short w0T[64 * SW0];   // [c][i] bf16
  __shared__ __align__(16) unsigned short w1T[64 * SW];
  __shared__ __align__(16) unsigned short w2T[64 * SW];
  __shared__ __align__(16) unsigned short wscT[64 * SW];
  __shared__ __align__(16) unsigned short X0[4][16 * SW0]; // per-wave act
  __shared__ __align__(16) unsigned short CFB[4][16 * SW]; // per-wave centers

  const int tid = threadIdx.x;
  const int wv = tid >> 6;
  const int lane = tid & 63;
  const int m = lane & 15;   // MFMA m/n within tile
  const int q4 = lane >> 4;  // MFMA quad

  // ---- stage weights transposed to bf16 (once per block) ----
#pragma unroll
  for (int q = 0; q < 8; ++q) {
    const int v = tid + 256 * q;           // float4 idx, 2048 total
    const float4 w = ((const float4*)w0)[v];
    const int i = v >> 4, c = (v & 15) << 2;
    w0T[(c + 0) * SW0 + i] = (unsigned short)f2b(w.x);
    w0T[(c + 1) * SW0 + i] = (unsigned short)f2b(w.y);
    w0T[(c + 2) * SW0 + i] = (unsigned short)f2b(w.z);
    w0T[(c + 3) * SW0 + i] = (unsigned short)f2b(w.w);
  }
#pragma unroll
  for (int q = 0; q < 4; ++q) {
    const int v = tid + 256 * q;           // 1024 total each
    const int i = v >> 4, c = (v & 15) << 2;
    float4 w = ((const float4*)w1)[v];
    w1T[(c + 0) * SW + i] = (unsigned short)f2b(w.x);
    w1T[(c + 1) * SW + i] = (unsigned short)f2b(w.y);
    w1T[(c + 2) * SW + i] = (unsigned short)f2b(w.z);
    w1T[(c + 3) * SW + i] = (unsigned short)f2b(w.w);
    w = ((const float4*)w2)[v];
    w2T[(c + 0) * SW + i] = (unsigned short)f2b(w.x);
    w2T[(c + 1) * SW + i] = (unsigned short)f2b(w.y);
    w2T[(c + 2) * SW + i] = (unsigned short)f2b(w.z);
    w2T[(c + 3) * SW + i] = (unsigned short)f2b(w.w);
    w = ((const float4*)wsc)[v];
    wscT[(c + 0) * SW + i] = (unsigned short)f2b(w.x);
    wscT[(c + 1) * SW + i] = (unsigned short)f2b(w.y);
    wscT[(c + 2) * SW + i] = (unsigned short)f2b(w.z);
    wscT[(c + 3) * SW + i] = (unsigned short)f2b(w.w);
  }

  // ---- folded BN affine, this lane's channel per n-tile: c = nt*16+m ----
  float s0[4], o0[4], s1[4], o1[4], s2[4], o2[4], ssc[4], osc[4];
#pragma unroll
  for (int nt = 0; nt < 4; ++nt) {
    const int c = nt * 16 + m;
    float s;
    s = g0[c] / sqrtf(v0[c] + EPSV); s0[nt] = s; o0[nt] = b0[c] - m0[c] * s;
    s = g1[c] / sqrtf(v1[c] + EPSV); s1[nt] = s; o1[nt] = b1[c] - m1[c] * s;
    s = g2[c] / sqrtf(v2[c] + EPSV); s2[nt] = s; o2[nt] = b2[c] - m2[c] * s;
    s = gsc[c] / sqrtf(vsc[c] + EPSV); ssc[nt] = s; osc[nt] = bsc[c] - msc[c] * s;
  }

  const int row0 = blockIdx.x * 64 + wv * 16;  // this wave's 16 rows
  // ---- stage this wave's 16 center rows as bf16 (shortcut A-operand) ----
  {
    const int r = lane >> 2, p = lane & 3;
    const float4* fr = (const float4*)(feat + (row0 + r) * 64);
    const float4 a = fr[p * 4 + 0], bq = fr[p * 4 + 1];
    const float4 cq = fr[p * 4 + 2], dq = fr[p * 4 + 3];
    uint4 u0, u1;
    u0.x = pk(a.x, a.y); u0.y = pk(a.z, a.w);
    u0.z = pk(bq.x, bq.y); u0.w = pk(bq.z, bq.w);
    u1.x = pk(cq.x, cq.y); u1.y = pk(cq.z, cq.w);
    u1.z = pk(dq.x, dq.y); u1.w = pk(dq.z, dq.w);
    *(uint4*)&CFB[wv][r * SW + p * 16] = u0;
    *(uint4*)&CFB[wv][r * SW + p * 16 + 8] = u1;
  }
  __syncthreads();  // weights visible to all waves

  // ---- shortcut: one M=16 GEMM over this wave's 16 rows ----
  const f32x4 fzero = {0.f, 0.f, 0.f, 0.f};
  f32x4 sacc[4] = {fzero, fzero, fzero, fzero};
#pragma unroll
  for (int t = 0; t < 2; ++t) {
    B8 af; af.u = *(const uint4*)&CFB[wv][m * SW + t * 32 + q4 * 8];
#pragma unroll
    for (int nt = 0; nt < 4; ++nt) {
      B8 bf_; bf_.u = *(const uint4*)&wscT[(nt * 16 + m) * SW + t * 32 + q4 * 8];
      sacc[nt] = __builtin_amdgcn_mfma_f32_16x16x32_bf16(af.v, bf_.v, sacc[nt], 0, 0, 0);
    }
  }
  float scf[4][4];  // [nt][reg]: row = q4*4+reg, channel nt*16+m, BN applied
#pragma unroll
  for (int nt = 0; nt < 4; ++nt)
#pragma unroll
    for (int r = 0; r < 4; ++r)
      scf[nt][r] = fmaf(sacc[nt][r], ssc[nt], osc[nt]);

  const float* featb = feat + (row0 >> 7) * (128 * 64);  // batch base
  const int kk = lane >> 2, pp = lane & 3;

  for (int qo = 0; qo < 4; ++qo) {
#pragma unroll
    for (int ri = 0; ri < 4; ++ri) {
      const int rr = qo * 4 + ri;
      const int row = row0 + rr;

      // ---- stage X0: rows k=0..15, cols [center(64) | nbr-center(64)] ----
      {
        const int j = knnIdx[row * KK + kk];
        const float4* np_ = (const float4*)(featb + j * 64);
        const float4* cp_ = (const float4*)(feat + row * 64);
        const float4 n0 = np_[pp * 4 + 0], n1 = np_[pp * 4 + 1];
        const float4 n2 = np_[pp * 4 + 2], n3 = np_[pp * 4 + 3];
        const float4 c0 = cp_[pp * 4 + 0], c1 = cp_[pp * 4 + 1];
        const float4 c2 = cp_[pp * 4 + 2], c3 = cp_[pp * 4 + 3];
        uint4 u;
        u.x = pk(c0.x, c0.y); u.y = pk(c0.z, c0.w);
        u.z = pk(c1.x, c1.y); u.w = pk(c1.z, c1.w);
        *(uint4*)&X0[wv][kk * SW0 + pp * 16] = u;
        u.x = pk(c2.x, c2.y); u.y = pk(c2.z, c2.w);
        u.z = pk(c3.x, c3.y); u.w = pk(c3.z, c3.w);
        *(uint4*)&X0[wv][kk * SW0 + pp * 16 + 8] = u;
        u.x = pk(n0.x - c0.x, n0.y - c0.y); u.y = pk(n0.z - c0.z, n0.w - c0.w);
        u.z = pk(n1.x - c1.x, n1.y - c1.y); u.w = pk(n1.z - c1.z, n1.w - c1.w);
        *(uint4*)&X0[wv][kk * SW0 + 64 + pp * 16] = u;
        u.x = pk(n2.x - c2.x, n2.y - c2.y); u.y = pk(n2.z - c2.z, n2.w - c2.w);
        u.z = pk(n3.x - c3.x, n3.y - c3.y); u.w = pk(n3.z - c3.z, n3.w - c3.w);
        *(uint4*)&X0[wv][kk * SW0 + 64 + pp * 16 + 8] = u;
      }

      // ---- layer 0: K=128 ----
      f32x4 acc[4] = {fzero, fzero, fzero, fzero};
#pragma unroll
      for (int t = 0; t < 4; ++t) {
        B8 af; af.u = *(const uint4*)&X0[wv][m * SW0 + t * 32 + q4 * 8];
#pragma unroll
        for (int nt = 0; nt < 4; ++nt) {
          B8 bf_; bf_.u = *(const uint4*)&w0T[(nt * 16 + m) * SW0 + t * 32 + q4 * 8];
          acc[nt] = __builtin_amdgcn_mfma_f32_16x16x32_bf16(af.v, bf_.v, acc[nt], 0, 0, 0);
        }
      }
#pragma unroll
      for (int nt = 0; nt < 4; ++nt)
#pragma unroll
        for (int r2 = 0; r2 < 4; ++r2) {
          const float y = fmaxf(fmaf(acc[nt][r2], s0[nt], o0[nt]), 0.f);
          X0[wv][(q4 * 4 + r2) * SW0 + nt * 16 + m] = (unsigned short)f2b(y);
        }

      // ---- layer 1: K=64 (in-place, in-wave DS ordering) ----
      acc[0] = fzero; acc[1] = fzero; acc[2] = fzero; acc[3] = fzero;
#pragma unroll
      for (int t = 0; t < 2; ++t) {
        B8 af; af.u = *(const uint4*)&X0[wv][m * SW0 + t * 32 + q4 * 8];
#pragma unroll
        for (int nt = 0; nt < 4; ++nt) {
          B8 bf_; bf_.u = *(const uint4*)&w1T[(nt * 16 + m) * SW + t * 32 + q4 * 8];
          acc[nt] = __builtin_amdgcn_mfma_f32_16x16x32_bf16(af.v, bf_.v, acc[nt], 0, 0, 0);
        }
      }
#pragma unroll
      for (int nt = 0; nt < 4; ++nt)
#pragma unroll
        for (int r2 = 0; r2 < 4; ++r2) {
          const float y = fmaxf(fmaf(acc[nt][r2], s1[nt], o1[nt]), 0.f);
          X0[wv][(q4 * 4 + r2) * SW0 + nt * 16 + m] = (unsigned short)f2b(y);
        }

      // ---- layer 2: K=64 ----
      acc[0] = fzero; acc[1] = fzero; acc[2] = fzero; acc[3] = fzero;
#pragma unroll
      for (int t = 0; t < 2; ++t) {
        B8 af; af.u = *(const uint4*)&X0[wv][m * SW0 + t * 32 + q4 * 8];
#pragma unroll
        for (int nt = 0; nt < 4; ++nt) {
          B8 bf_; bf_.u = *(const uint4*)&w2T[(nt * 16 + m) * SW + t * 32 + q4 * 8];
          acc[nt] = __builtin_amdgcn_mfma_f32_16x16x32_bf16(af.v, bf_.v, acc[nt], 0, 0, 0);
        }
      }

      // ---- BN+ReLU, mean over k, add shortcut, store ----
      float pool[4];
#pragma unroll
      for (int nt = 0; nt < 4; ++nt) {
        float p_ = 0.f;
#pragma unroll
        for (int r2 = 0; r2 < 4; ++r2)
          p_ += fmaxf(fmaf(acc[nt][r2], s2[nt], o2[nt]), 0.f);
        p_ += __shfl_xor(p_, 16);
        p_ += __shfl_xor(p_, 32);
        pool[nt] = p_ * 0.0625f;
      }
      if (q4 == qo) {
#pragma unroll
        for (int nt = 0; nt < 4; ++nt)
          out[row * 64 + nt * 16 + m] = fmaxf(scf[nt][ri] + pool[nt], 0.f);
      }
    }
  }
}

extern "C" void kernel_launch(void* const* d_in, const int* in_sizes, int n_in,
                              void* d_out, int out_size, void* d_ws, size_t ws_size,
                              hipStream_t stream) {
  const float* pts = (const float*)d_in[0];
  const float* feat = (const float*)d_in[1];
  const float* w0 = (const float*)d_in[2];
  const float* g0 = (const float*)d_in[3];
  const float* b0 = (const float*)d_in[4];
  const float* m0 = (const float*)d_in[5];
  const float* v0 = (const float*)d_in[6];
  const float* w1 = (const float*)d_in[7];
  const float* g1 = (const float*)d_in[8];
  const float* b1 = (const float*)d_in[9];
  const float* m1 = (const float*)d_in[10];
  const float* v1 = (const float*)d_in[11];
  const float* w2 = (const float*)d_in[12];
  const float* g2 = (const float*)d_in[13];
  const float* b2 = (const float*)d_in[14];
  const float* m2 = (const float*)d_in[15];
  const float* v2 = (const float*)d_in[16];
  const float* wsc = (const float*)d_in[17];
  const float* gsc = (const float*)d_in[18];
  const float* bsc = (const float*)d_in[19];
  const float* msc = (const float*)d_in[20];
  const float* vsc = (const float*)d_in[21];
  float* out = (float*)d_out;

  int* knn = (int*)d_ws;  // 256*128*16 ints = 2 MB

  knn_kernel<<<dim3(256 * 128 / 4), dim3(256), 0, stream>>>(pts, knn);
  mlp_kernel<<<dim3(512), dim3(256), 0, stream>>>(
      feat, knn, w0, g0, b0, m0, v0, w1, g1, b1, m1, v1, w2, g2, b2, m2, v2,
      wsc, gsc, bsc, msc, vsc, out);
}